// Round 1
// baseline (554.544 us; speedup 1.0000x reference)
//
#include <hip/hip_runtime.h>
#include <hip/hip_bf16.h>

#define B_ 8
#define S_ 2048
#define E_ 1024

using f32x4 = __attribute__((ext_vector_type(4))) float;
using s16x8 = __attribute__((ext_vector_type(8))) short;
using u16x8 = __attribute__((ext_vector_type(8))) unsigned short;

typedef __attribute__((address_space(1))) unsigned int glb_u32;
typedef __attribute__((address_space(3))) unsigned int lds_u32;

static __device__ __forceinline__ unsigned short f2bf(float f) {
    union { float f; unsigned int u; } v; v.f = f;
    unsigned int u = v.u;
    u += 0x7FFFu + ((u >> 16) & 1u);   // round-to-nearest-even
    return (unsigned short)(u >> 16);
}
static __device__ __forceinline__ float bf2f(unsigned short h) {
    union { unsigned int u; float f; } v; v.u = ((unsigned int)h) << 16;
    return v.f;
}

// ---------------------------------------------------------------------------
// Mask canonicalizer: the jax bool mask may arrive as uint8, int32 or float32.
// Detect layout from byte pattern (values are only 0/1), emit canonical uint8.
// Safe: scans only the first n bytes (minimum possible buffer size).
// ---------------------------------------------------------------------------
__global__ __launch_bounds__(256) void mask_canon_kernel(
    const unsigned char* __restrict__ src, unsigned char* __restrict__ dst, int n)
{
    __shared__ int flags;
    if (threadIdx.x == 0) flags = 0;
    __syncthreads();
    int f = 0;
    for (int j = threadIdx.x; j < n; j += 256) {
        unsigned char b = src[j];
        if (b) {
            int p = j & 3;
            if (p == 1) f |= 1;   // only uint8 layout has nonzero at %4==1
            if (p >= 2) f |= 2;   // uint8 or float32
        }
    }
    if (f) atomicOr(&flags, f);
    __syncthreads();
    const int fl = flags;
    for (int i = threadIdx.x; i < n; i += 256) {
        unsigned char v;
        if (fl & 1)      v = (unsigned char)(src[i] != 0);                      // uint8
        else if (fl & 2) v = (unsigned char)(((const float*)(const void*)src)[i] != 0.0f); // f32
        else             v = (unsigned char)(((const int*)(const void*)src)[i] != 0);      // int32
        dst[i] = v;
    }
}

// ---------------------------------------------------------------------------
// Projection GEMM (NT): C[m,n] = sum_k A[m,k]*B[n,k] + bias, fp32 in, bf16 out.
// 128x128 tile, BK=32, 4 waves (2x2), 16x16x32 bf16 MFMA, cvt during staging.
// BIAS_ROW=false: bias[n] (Q/K);  BIAS_ROW=true: bias[m] (V^T mode, A=W B=x).
// ---------------------------------------------------------------------------
template<bool BIAS_ROW>
__global__ __launch_bounds__(256) void proj_gemm(
    const float* __restrict__ A, const float* __restrict__ B,
    const float* __restrict__ bias, unsigned short* __restrict__ C,
    int K, int lda, int ldb, int ldc)
{
    __shared__ unsigned short sA[128 * 32];
    __shared__ unsigned short sB[128 * 32];
    const int tid = threadIdx.x;
    const int m0 = blockIdx.y * 128, n0 = blockIdx.x * 128;
    const int lane = tid & 63, w = tid >> 6;
    const int wr = w >> 1, wc = w & 1;
    const int fr = lane & 15, fk = (lane >> 4) * 8;
    const int rowA = tid >> 2, colT = (tid & 3) * 8;

    f32x4 acc[4][4] = {};

    for (int k0 = 0; k0 < K; k0 += 32) {
        __syncthreads();
        #pragma unroll
        for (int it = 0; it < 2; ++it) {
            const int row = it * 64 + rowA;
            const float* ga = A + (size_t)(m0 + row) * lda + (k0 + colT);
            const float* gb = B + (size_t)(n0 + row) * ldb + (k0 + colT);
            float4 a0 = *(const float4*)ga, a1 = *(const float4*)(ga + 4);
            float4 b0 = *(const float4*)gb, b1 = *(const float4*)(gb + 4);
            u16x8 pa, pb;
            pa[0]=f2bf(a0.x); pa[1]=f2bf(a0.y); pa[2]=f2bf(a0.z); pa[3]=f2bf(a0.w);
            pa[4]=f2bf(a1.x); pa[5]=f2bf(a1.y); pa[6]=f2bf(a1.z); pa[7]=f2bf(a1.w);
            pb[0]=f2bf(b0.x); pb[1]=f2bf(b0.y); pb[2]=f2bf(b0.z); pb[3]=f2bf(b0.w);
            pb[4]=f2bf(b1.x); pb[5]=f2bf(b1.y); pb[6]=f2bf(b1.z); pb[7]=f2bf(b1.w);
            *(u16x8*)&sA[row * 32 + colT] = pa;
            *(u16x8*)&sB[row * 32 + colT] = pb;
        }
        __syncthreads();
        s16x8 af[4], bfr[4];
        #pragma unroll
        for (int i = 0; i < 4; ++i) af[i]  = *(const s16x8*)&sA[(wr*64 + i*16 + fr)*32 + fk];
        #pragma unroll
        for (int j = 0; j < 4; ++j) bfr[j] = *(const s16x8*)&sB[(wc*64 + j*16 + fr)*32 + fk];
        #pragma unroll
        for (int i = 0; i < 4; ++i)
            #pragma unroll
            for (int j = 0; j < 4; ++j)
                acc[i][j] = __builtin_amdgcn_mfma_f32_16x16x32_bf16(af[i], bfr[j], acc[i][j], 0, 0, 0);
    }

    #pragma unroll
    for (int j = 0; j < 4; ++j) {
        const int ncol = n0 + wc*64 + j*16 + (lane & 15);
        #pragma unroll
        for (int i = 0; i < 4; ++i) {
            #pragma unroll
            for (int r = 0; r < 4; ++r) {
                const int mrow = m0 + wr*64 + i*16 + (lane >> 4) * 4 + r;
                float val = acc[i][j][r] + (BIAS_ROW ? bias[mrow] : bias[ncol]);
                C[(size_t)mrow * ldc + ncol] = f2bf(val);
            }
        }
    }
}

// ---------------------------------------------------------------------------
// bf16 NT GEMM, global_load_lds staging. EPI=0: QK epilogue (scale+mask->bf16),
// EPI=1: PV epilogue (fp32 store).
// ---------------------------------------------------------------------------
template<int EPI>
__global__ __launch_bounds__(256) void gemm_bf16_nt(
    const unsigned short* __restrict__ A, const unsigned short* __restrict__ B,
    void* __restrict__ Cout,
    long long sAz, long long sBz, long long sCz,
    int lda, int ldb, int ldc, int K,
    const unsigned char* __restrict__ mask, int maskStride, float scale)
{
    __shared__ unsigned short sA[128 * 32];
    __shared__ unsigned short sB[128 * 32];
    const int tid = threadIdx.x;
    const int z = blockIdx.z;
    const unsigned short* Ab = A + (size_t)z * sAz;
    const unsigned short* Bb = B + (size_t)z * sBz;
    const int m0 = blockIdx.y * 128, n0 = blockIdx.x * 128;
    const int lane = tid & 63, w = tid >> 6;
    const int wr = w >> 1, wc = w & 1;
    const int fr = lane & 15, fk = (lane >> 4) * 8;
    const int rowA = tid >> 2, colT = (tid & 3) * 8;

    f32x4 acc[4][4] = {};

    for (int k0 = 0; k0 < K; k0 += 32) {
        __syncthreads();
        #pragma unroll
        for (int it = 0; it < 2; ++it) {
            const int row = it * 64 + rowA;
            const unsigned short* ga = Ab + (size_t)(m0 + row) * lda + (k0 + colT);
            const unsigned short* gb = Bb + (size_t)(n0 + row) * ldb + (k0 + colT);
            const int ubase = (it * 256 + (tid & ~63)) * 8;   // wave-uniform LDS base
            __builtin_amdgcn_global_load_lds((const glb_u32*)ga, (lds_u32*)&sA[ubase], 16, 0, 0);
            __builtin_amdgcn_global_load_lds((const glb_u32*)gb, (lds_u32*)&sB[ubase], 16, 0, 0);
        }
        __syncthreads();
        s16x8 af[4], bfr[4];
        #pragma unroll
        for (int i = 0; i < 4; ++i) af[i]  = *(const s16x8*)&sA[(wr*64 + i*16 + fr)*32 + fk];
        #pragma unroll
        for (int j = 0; j < 4; ++j) bfr[j] = *(const s16x8*)&sB[(wc*64 + j*16 + fr)*32 + fk];
        #pragma unroll
        for (int i = 0; i < 4; ++i)
            #pragma unroll
            for (int j = 0; j < 4; ++j)
                acc[i][j] = __builtin_amdgcn_mfma_f32_16x16x32_bf16(af[i], bfr[j], acc[i][j], 0, 0, 0);
    }

    if constexpr (EPI == 0) {
        unsigned short* Cb = (unsigned short*)Cout + (size_t)z * sCz;
        const unsigned char* mb = mask + (size_t)z * maskStride;
        #pragma unroll
        for (int j = 0; j < 4; ++j) {
            const int ncol = n0 + wc*64 + j*16 + (lane & 15);
            const bool msk = mb[ncol] != 0;
            #pragma unroll
            for (int i = 0; i < 4; ++i) {
                #pragma unroll
                for (int r = 0; r < 4; ++r) {
                    const int mrow = m0 + wr*64 + i*16 + (lane >> 4) * 4 + r;
                    float val = msk ? 1e-9f : acc[i][j][r] * scale;
                    Cb[(size_t)mrow * ldc + ncol] = f2bf(val);
                }
            }
        }
    } else {
        float* Cb = (float*)Cout + (size_t)z * sCz;
        #pragma unroll
        for (int j = 0; j < 4; ++j) {
            const int ncol = n0 + wc*64 + j*16 + (lane & 15);
            #pragma unroll
            for (int i = 0; i < 4; ++i) {
                #pragma unroll
                for (int r = 0; r < 4; ++r) {
                    const int mrow = m0 + wr*64 + i*16 + (lane >> 4) * 4 + r;
                    Cb[(size_t)mrow * ldc + ncol] = acc[i][j][r];
                }
            }
        }
    }
}

// ---------------------------------------------------------------------------
// Row softmax over S_=2048 bf16 scores, in place. One block per row.
// Matches jax: exp(x - max) / sum.
// ---------------------------------------------------------------------------
__global__ __launch_bounds__(256) void softmax_kernel(unsigned short* __restrict__ P)
{
    const int row = blockIdx.x;
    const int tid = threadIdx.x;
    unsigned short* prow = P + (size_t)row * S_;
    u16x8 v = *(const u16x8*)&prow[tid * 8];
    float f[8];
    #pragma unroll
    for (int j = 0; j < 8; ++j) f[j] = bf2f(v[j]);
    float m = f[0];
    #pragma unroll
    for (int j = 1; j < 8; ++j) m = fmaxf(m, f[j]);
    #pragma unroll
    for (int o = 1; o < 64; o <<= 1) m = fmaxf(m, __shfl_xor(m, o, 64));
    __shared__ float smax[4], ssum[4];
    const int w = tid >> 6, lane = tid & 63;
    if (lane == 0) smax[w] = m;
    __syncthreads();
    m = fmaxf(fmaxf(smax[0], smax[1]), fmaxf(smax[2], smax[3]));
    float e[8], s = 0.f;
    #pragma unroll
    for (int j = 0; j < 8; ++j) { e[j] = expf(f[j] - m); s += e[j]; }
    #pragma unroll
    for (int o = 1; o < 64; o <<= 1) s += __shfl_xor(s, o, 64);
    if (lane == 0) ssum[w] = s;
    __syncthreads();
    s = ssum[0] + ssum[1] + ssum[2] + ssum[3];
    const float inv = 1.0f / s;
    u16x8 o8;
    #pragma unroll
    for (int j = 0; j < 8; ++j) o8[j] = f2bf(e[j] * inv);
    *(u16x8*)&prow[tid * 8] = o8;
}

// ---------------------------------------------------------------------------
extern "C" void kernel_launch(void* const* d_in, const int* in_sizes, int n_in,
                              void* d_out, int out_size, void* d_ws, size_t ws_size,
                              hipStream_t stream)
{
    const float* x  = (const float*)d_in[0];
    const float* Wq = (const float*)d_in[1];
    const float* bq = (const float*)d_in[2];
    const float* Wk = (const float*)d_in[3];
    const float* bk = (const float*)d_in[4];
    const float* Wv = (const float*)d_in[5];
    const float* bv = (const float*)d_in[6];
    const unsigned char* mraw = (const unsigned char*)d_in[7];

    const int BS = B_ * S_;                      // 16384
    // ws layout: Q (32M) | K (32M) | V^T (32M) | scores/P (64M) | mask (16K)
    unsigned short* Qb = (unsigned short*)d_ws;
    unsigned short* Kb = Qb + (size_t)BS * E_;
    unsigned short* VT = Kb + (size_t)BS * E_;
    unsigned short* Sc = VT + (size_t)E_ * BS;
    unsigned char* mcanon = (unsigned char*)(Sc + (size_t)B_ * S_ * S_);

    mask_canon_kernel<<<1, 256, 0, stream>>>(mraw, mcanon, BS);

    // Q = x @ Wq^T + bq ; K = x @ Wk^T + bk   (row-major [BS][E], bf16)
    proj_gemm<false><<<dim3(E_ / 128, BS / 128), 256, 0, stream>>>(x, Wq, bq, Qb, E_, E_, E_, E_);
    proj_gemm<false><<<dim3(E_ / 128, BS / 128), 256, 0, stream>>>(x, Wk, bk, Kb, E_, E_, E_, E_);
    // V^T[e][b*S+s] = Wv[e,:] . x[b,s,:] + bv[e]  (A=Wv rows=e, B=x rows=s)
    proj_gemm<true ><<<dim3(BS / 128, E_ / 128), 256, 0, stream>>>(Wv, x, bv, VT, E_, E_, E_, BS);

    // scores[b,q,k] = (Q.K^T)/32, mask fill 1e-9, bf16
    gemm_bf16_nt<0><<<dim3(S_ / 128, S_ / 128, B_), 256, 0, stream>>>(
        Qb, Kb, (void*)Sc,
        (long long)S_ * E_, (long long)S_ * E_, (long long)S_ * S_,
        E_, E_, S_, E_, mcanon, S_, 0.03125f);

    // softmax along k (in place)
    softmax_kernel<<<dim3(BS), 256, 0, stream>>>(Sc);

    // out[b,q,e] = P . V  (via V^T, NT)
    gemm_bf16_nt<1><<<dim3(E_ / 128, S_ / 128, B_), 256, 0, stream>>>(
        Sc, VT, d_out,
        (long long)S_ * S_, (long long)S_, (long long)S_ * E_,
        S_, BS, E_, S_, nullptr, 0, 1.0f);
}

// Round 2
// 474.687 us; speedup vs baseline: 1.1682x; 1.1682x over previous
//
#include <hip/hip_runtime.h>
#include <hip/hip_bf16.h>

#define B_ 8
#define S_ 2048
#define E_ 1024

using f32x4 = __attribute__((ext_vector_type(4))) float;
using s16x8 = __attribute__((ext_vector_type(8))) short;
using u16x8 = __attribute__((ext_vector_type(8))) unsigned short;

typedef __attribute__((address_space(1))) unsigned int glb_u32;
typedef __attribute__((address_space(3))) unsigned int lds_u32;

static __device__ __forceinline__ unsigned short f2bf(float f) {
    union { float f; unsigned int u; } v; v.f = f;
    unsigned int u = v.u;
    u += 0x7FFFu + ((u >> 16) & 1u);   // round-to-nearest-even
    return (unsigned short)(u >> 16);
}
static __device__ __forceinline__ float bf2f(unsigned short h) {
    union { unsigned int u; float f; } v; v.u = ((unsigned int)h) << 16;
    return v.f;
}

// ---------------------------------------------------------------------------
// Mask canonicalizer: jax bool mask may arrive as uint8, int32 or float32.
// ---------------------------------------------------------------------------
__global__ __launch_bounds__(256) void mask_canon_kernel(
    const unsigned char* __restrict__ src, unsigned char* __restrict__ dst, int n)
{
    __shared__ int flags;
    if (threadIdx.x == 0) flags = 0;
    __syncthreads();
    int f = 0;
    for (int j = threadIdx.x; j < n; j += 256) {
        unsigned char b = src[j];
        if (b) {
            int p = j & 3;
            if (p == 1) f |= 1;   // only uint8 layout has nonzero at %4==1
            if (p >= 2) f |= 2;   // uint8 or float32
        }
    }
    if (f) atomicOr(&flags, f);
    __syncthreads();
    const int fl = flags;
    for (int i = threadIdx.x; i < n; i += 256) {
        unsigned char v;
        if (fl & 1)      v = (unsigned char)(src[i] != 0);
        else if (fl & 2) v = (unsigned char)(((const float*)(const void*)src)[i] != 0.0f);
        else             v = (unsigned char)(((const int*)(const void*)src)[i] != 0);
        dst[i] = v;
    }
}

// ---------------------------------------------------------------------------
// fp32 -> bf16 bulk convert, 8 elems/thread, grid-stride.
// ---------------------------------------------------------------------------
__global__ __launch_bounds__(256) void cvt_bf16_kernel(
    const float* __restrict__ src, unsigned short* __restrict__ dst, int n8)
{
    const int stride = gridDim.x * 256;
    for (int i = blockIdx.x * 256 + threadIdx.x; i < n8; i += stride) {
        float4 a = *(const float4*)(src + (size_t)i * 8);
        float4 b = *(const float4*)(src + (size_t)i * 8 + 4);
        u16x8 o;
        o[0]=f2bf(a.x); o[1]=f2bf(a.y); o[2]=f2bf(a.z); o[3]=f2bf(a.w);
        o[4]=f2bf(b.x); o[5]=f2bf(b.y); o[6]=f2bf(b.z); o[7]=f2bf(b.w);
        *(u16x8*)(dst + (size_t)i * 8) = o;
    }
}

// ---------------------------------------------------------------------------
// bf16 NT GEMM, global_load_lds staging, 128x128 tile, 16x16x32 bf16 MFMA.
// EPI=0: QK (scale + mask-fill 1e-9 -> bf16)
// EPI=1: PV (fp32 store)
// EPI=2: bias[ncol] -> bf16   (Q/K projection)
// EPI=3: bias[mrow] -> bf16   (V^T projection)
// ---------------------------------------------------------------------------
template<int EPI>
__global__ __launch_bounds__(256) void gemm_bf16_nt(
    const unsigned short* __restrict__ A, const unsigned short* __restrict__ B,
    void* __restrict__ Cout,
    long long sAz, long long sBz, long long sCz,
    int lda, int ldb, int ldc, int K,
    const unsigned char* __restrict__ mask, int maskStride, float scale,
    const float* __restrict__ bias)
{
    __shared__ unsigned short sA[128 * 32];
    __shared__ unsigned short sB[128 * 32];
    const int tid = threadIdx.x;
    const int z = blockIdx.z;
    const unsigned short* Ab = A + (size_t)z * sAz;
    const unsigned short* Bb = B + (size_t)z * sBz;
    const int m0 = blockIdx.y * 128, n0 = blockIdx.x * 128;
    const int lane = tid & 63, w = tid >> 6;
    const int wr = w >> 1, wc = w & 1;
    const int fr = lane & 15, fk = (lane >> 4) * 8;
    const int rowA = tid >> 2, colT = (tid & 3) * 8;

    f32x4 acc[4][4] = {};

    for (int k0 = 0; k0 < K; k0 += 32) {
        __syncthreads();
        #pragma unroll
        for (int it = 0; it < 2; ++it) {
            const int row = it * 64 + rowA;
            const unsigned short* ga = Ab + (size_t)(m0 + row) * lda + (k0 + colT);
            const unsigned short* gb = Bb + (size_t)(n0 + row) * ldb + (k0 + colT);
            const int ubase = (it * 256 + (tid & ~63)) * 8;   // wave-uniform LDS base
            __builtin_amdgcn_global_load_lds((const glb_u32*)ga, (lds_u32*)&sA[ubase], 16, 0, 0);
            __builtin_amdgcn_global_load_lds((const glb_u32*)gb, (lds_u32*)&sB[ubase], 16, 0, 0);
        }
        __syncthreads();
        s16x8 af[4], bfr[4];
        #pragma unroll
        for (int i = 0; i < 4; ++i) af[i]  = *(const s16x8*)&sA[(wr*64 + i*16 + fr)*32 + fk];
        #pragma unroll
        for (int j = 0; j < 4; ++j) bfr[j] = *(const s16x8*)&sB[(wc*64 + j*16 + fr)*32 + fk];
        #pragma unroll
        for (int i = 0; i < 4; ++i)
            #pragma unroll
            for (int j = 0; j < 4; ++j)
                acc[i][j] = __builtin_amdgcn_mfma_f32_16x16x32_bf16(af[i], bfr[j], acc[i][j], 0, 0, 0);
    }

    if constexpr (EPI == 1) {
        float* Cb = (float*)Cout + (size_t)z * sCz;
        #pragma unroll
        for (int j = 0; j < 4; ++j) {
            const int ncol = n0 + wc*64 + j*16 + (lane & 15);
            #pragma unroll
            for (int i = 0; i < 4; ++i)
                #pragma unroll
                for (int r = 0; r < 4; ++r) {
                    const int mrow = m0 + wr*64 + i*16 + (lane >> 4) * 4 + r;
                    Cb[(size_t)mrow * ldc + ncol] = acc[i][j][r];
                }
        }
    } else {
        unsigned short* Cb = (unsigned short*)Cout + (size_t)z * sCz;
        const unsigned char* mb = (EPI == 0) ? mask + (size_t)z * maskStride : nullptr;
        #pragma unroll
        for (int j = 0; j < 4; ++j) {
            const int ncol = n0 + wc*64 + j*16 + (lane & 15);
            bool msk = false; float bn = 0.f;
            if constexpr (EPI == 0) msk = mb[ncol] != 0;
            if constexpr (EPI == 2) bn = bias[ncol];
            #pragma unroll
            for (int i = 0; i < 4; ++i) {
                #pragma unroll
                for (int r = 0; r < 4; ++r) {
                    const int mrow = m0 + wr*64 + i*16 + (lane >> 4) * 4 + r;
                    float val;
                    if constexpr (EPI == 0)      val = msk ? 1e-9f : acc[i][j][r] * scale;
                    else if constexpr (EPI == 2) val = acc[i][j][r] + bn;
                    else                         val = acc[i][j][r] + bias[mrow];
                    Cb[(size_t)mrow * ldc + ncol] = f2bf(val);
                }
            }
        }
    }
}

// ---------------------------------------------------------------------------
// Row softmax over S_=2048 bf16 scores, in place. One block per row.
// ---------------------------------------------------------------------------
__global__ __launch_bounds__(256) void softmax_kernel(unsigned short* __restrict__ P)
{
    const int row = blockIdx.x;
    const int tid = threadIdx.x;
    unsigned short* prow = P + (size_t)row * S_;
    u16x8 v = *(const u16x8*)&prow[tid * 8];
    float f[8];
    #pragma unroll
    for (int j = 0; j < 8; ++j) f[j] = bf2f(v[j]);
    float m = f[0];
    #pragma unroll
    for (int j = 1; j < 8; ++j) m = fmaxf(m, f[j]);
    #pragma unroll
    for (int o = 1; o < 64; o <<= 1) m = fmaxf(m, __shfl_xor(m, o, 64));
    __shared__ float smax[4], ssum[4];
    const int w = tid >> 6, lane = tid & 63;
    if (lane == 0) smax[w] = m;
    __syncthreads();
    m = fmaxf(fmaxf(smax[0], smax[1]), fmaxf(smax[2], smax[3]));
    float e[8], s = 0.f;
    #pragma unroll
    for (int j = 0; j < 8; ++j) { e[j] = expf(f[j] - m); s += e[j]; }
    #pragma unroll
    for (int o = 1; o < 64; o <<= 1) s += __shfl_xor(s, o, 64);
    if (lane == 0) ssum[w] = s;
    __syncthreads();
    s = ssum[0] + ssum[1] + ssum[2] + ssum[3];
    const float inv = 1.0f / s;
    u16x8 o8;
    #pragma unroll
    for (int j = 0; j < 8; ++j) o8[j] = f2bf(e[j] * inv);
    *(u16x8*)&prow[tid * 8] = o8;
}

// ---------------------------------------------------------------------------
extern "C" void kernel_launch(void* const* d_in, const int* in_sizes, int n_in,
                              void* d_out, int out_size, void* d_ws, size_t ws_size,
                              hipStream_t stream)
{
    const float* x  = (const float*)d_in[0];
    const float* Wq = (const float*)d_in[1];
    const float* bq = (const float*)d_in[2];
    const float* Wk = (const float*)d_in[3];
    const float* bk = (const float*)d_in[4];
    const float* Wv = (const float*)d_in[5];
    const float* bv = (const float*)d_in[6];
    const unsigned char* mraw = (const unsigned char*)d_in[7];

    const int BS = B_ * S_;                      // 16384
    // ws layout: Q (32M) | K (32M) | VT (32M) | Sc (64M) | mask
    // x_bf16 + W_bf16 alias the Sc region (dead before QK writes scores).
    unsigned short* Qb = (unsigned short*)d_ws;
    unsigned short* Kb = Qb + (size_t)BS * E_;
    unsigned short* VT = Kb + (size_t)BS * E_;
    unsigned short* Sc = VT + (size_t)BS * E_;
    unsigned short* xb = Sc;                                    // 32MB alias
    unsigned short* Wqb = Sc + (size_t)BS * E_;                 // +32MB
    unsigned short* Wkb = Wqb + (size_t)E_ * E_;
    unsigned short* Wvb = Wkb + (size_t)E_ * E_;                // ends +38MB < 64MB
    unsigned char* mcanon = (unsigned char*)(Sc + (size_t)B_ * S_ * S_);

    mask_canon_kernel<<<1, 256, 0, stream>>>(mraw, mcanon, BS);

    // bf16 conversions
    cvt_bf16_kernel<<<2048, 256, 0, stream>>>(x, xb, BS * E_ / 8);
    cvt_bf16_kernel<<<512, 256, 0, stream>>>(Wq, Wqb, E_ * E_ / 8);
    cvt_bf16_kernel<<<512, 256, 0, stream>>>(Wk, Wkb, E_ * E_ / 8);
    cvt_bf16_kernel<<<512, 256, 0, stream>>>(Wv, Wvb, E_ * E_ / 8);

    // Q = xb @ Wq^T + bq ; K = xb @ Wk^T + bk   (row-major [BS][E], bf16)
    gemm_bf16_nt<2><<<dim3(E_ / 128, BS / 128), 256, 0, stream>>>(
        xb, Wqb, (void*)Qb, 0, 0, 0, E_, E_, E_, E_, nullptr, 0, 1.0f, bq);
    gemm_bf16_nt<2><<<dim3(E_ / 128, BS / 128), 256, 0, stream>>>(
        xb, Wkb, (void*)Kb, 0, 0, 0, E_, E_, E_, E_, nullptr, 0, 1.0f, bk);
    // VT[e][bs] = Wv[e,:] . x[bs,:] + bv[e]
    gemm_bf16_nt<3><<<dim3(BS / 128, E_ / 128), 256, 0, stream>>>(
        Wvb, xb, (void*)VT, 0, 0, 0, E_, E_, BS, E_, nullptr, 0, 1.0f, bv);

    // scores[b,q,k] = (Q.K^T)/32, mask fill 1e-9, bf16
    gemm_bf16_nt<0><<<dim3(S_ / 128, S_ / 128, B_), 256, 0, stream>>>(
        Qb, Kb, (void*)Sc,
        (long long)S_ * E_, (long long)S_ * E_, (long long)S_ * S_,
        E_, E_, S_, E_, mcanon, S_, 0.03125f, nullptr);

    // softmax along k (in place)
    softmax_kernel<<<dim3(BS), 256, 0, stream>>>(Sc);

    // out[b,q,e] = P . V  (via V^T, NT)
    gemm_bf16_nt<1><<<dim3(E_ / 128, S_ / 128, B_), 256, 0, stream>>>(
        Sc, VT, d_out,
        (long long)S_ * S_, (long long)S_, (long long)S_ * E_,
        S_, BS, E_, S_, nullptr, 0, 1.0f, nullptr);
}

// Round 4
// 358.894 us; speedup vs baseline: 1.5451x; 1.3226x over previous
//
#include <hip/hip_runtime.h>
#include <hip/hip_bf16.h>

#define B_ 8
#define S_ 2048
#define E_ 1024

using f32x4 = __attribute__((ext_vector_type(4))) float;
using s16x8 = __attribute__((ext_vector_type(8))) short;
using u16x8 = __attribute__((ext_vector_type(8))) unsigned short;

typedef __attribute__((address_space(1))) unsigned int glb_u32;
typedef __attribute__((address_space(3))) unsigned int lds_u32;

static __device__ __forceinline__ unsigned short f2bf(float f) {
    union { float f; unsigned int u; } v; v.f = f;
    unsigned int u = v.u;
    u += 0x7FFFu + ((u >> 16) & 1u);   // round-to-nearest-even
    return (unsigned short)(u >> 16);
}
static __device__ __forceinline__ float bf2f(unsigned short h) {
    union { unsigned int u; float f; } v; v.u = ((unsigned int)h) << 16;
    return v.f;
}

// ---------------------------------------------------------------------------
// Mask canonicalizer: jax bool mask may arrive as uint8, int32 or float32.
// ---------------------------------------------------------------------------
__global__ __launch_bounds__(256) void mask_canon_kernel(
    const unsigned char* __restrict__ src, unsigned char* __restrict__ dst, int n)
{
    __shared__ int flags;
    if (threadIdx.x == 0) flags = 0;
    __syncthreads();
    int f = 0;
    for (int j = threadIdx.x; j < n; j += 256) {
        unsigned char b = src[j];
        if (b) {
            int p = j & 3;
            if (p == 1) f |= 1;
            if (p >= 2) f |= 2;
        }
    }
    if (f) atomicOr(&flags, f);
    __syncthreads();
    const int fl = flags;
    for (int i = threadIdx.x; i < n; i += 256) {
        unsigned char v;
        if (fl & 1)      v = (unsigned char)(src[i] != 0);
        else if (fl & 2) v = (unsigned char)(((const float*)(const void*)src)[i] != 0.0f);
        else             v = (unsigned char)(((const int*)(const void*)src)[i] != 0);
        dst[i] = v;
    }
}

// ---------------------------------------------------------------------------
// fp32 -> bf16 bulk convert.
// ---------------------------------------------------------------------------
__global__ __launch_bounds__(256) void cvt_bf16_kernel(
    const float* __restrict__ src, unsigned short* __restrict__ dst, int n8)
{
    const int stride = gridDim.x * 256;
    for (int i = blockIdx.x * 256 + threadIdx.x; i < n8; i += stride) {
        float4 a = *(const float4*)(src + (size_t)i * 8);
        float4 b = *(const float4*)(src + (size_t)i * 8 + 4);
        u16x8 o;
        o[0]=f2bf(a.x); o[1]=f2bf(a.y); o[2]=f2bf(a.z); o[3]=f2bf(a.w);
        o[4]=f2bf(b.x); o[5]=f2bf(b.y); o[6]=f2bf(b.z); o[7]=f2bf(b.w);
        *(u16x8*)(dst + (size_t)i * 8) = o;
    }
}

// ---------------------------------------------------------------------------
// 256x256 8-phase bf16 NT GEMM (m201 template, plain HIP).
//  - 8 waves (2M x 4N), each owns a 128x64 C region; BK=64; LDS 128KB 2-buf.
//  - st_16x32 XOR swizzle via pre-swizzled global SOURCE + swizzled read.
//  - Phase-1 reads all 24 frags, lgkmcnt(0) BEFORE the phase-2-entry barrier
//    => all waves' reads complete before any wave overwrites the live buffer.
//  - vmcnt(6) once per K-tile (exactly tile t+2's {A0,A1,B0} stay in flight).
// EPI: 0=QK(scale+mask->bf16) 1=PV(f32) 2=bias[ncol]->bf16 3=bias[mrow]->bf16
// ---------------------------------------------------------------------------
template<int EPI>
__global__ __launch_bounds__(512, 2) void gemm256(
    const unsigned short* __restrict__ A, const unsigned short* __restrict__ B,
    void* __restrict__ Cout,
    long long sAz, long long sBz, long long sCz,
    int lda, int ldb, int ldc, int K,
    const unsigned char* __restrict__ mask, int maskStride, float scale,
    const float* __restrict__ bias)
{
    __shared__ unsigned short lds[65536];   // 128 KB
    const int tid = threadIdx.x;
    const int lane = tid & 63, w = tid >> 6;
    const int wr = w >> 2, wc = w & 3;          // 2 x 4 waves
    const int fr = lane & 15, ch = lane >> 4;

    // T1: XCD-aware chunked swizzle of flattened block id (nwg % 8 == 0)
    const int gx = gridDim.x, gy = gridDim.y;
    const int nwg = gx * gy * gridDim.z;
    int bid = blockIdx.x + gx * (blockIdx.y + gy * blockIdx.z);
    bid = (bid & 7) * (nwg >> 3) + (bid >> 3);
    const int bx = bid % gx; int tmp = bid / gx;
    const int by = tmp % gy; const int bz = tmp / gy;

    const unsigned short* Ab = A + (size_t)bz * sAz;
    const unsigned short* Bb = B + (size_t)bz * sBz;
    const int m0 = by * 256, n0 = bx * 256;

    // swizzled frag-read lane offset (ushort units)
    const int rdlane = fr * 32 + ((ch * 8) ^ ((fr & 8) ? 16 : 0));
    // stage source mapping (inverse swizzle of the linear lane->phys write)
    const int local = (lane * 16) ^ (lane & 32);
    const int rloc = local >> 6;          // row within 16-row chunk
    const int cloc = (local >> 4) & 3;    // 16B col chunk

    f32x4 acc[8][4] = {};
    const int NT = K >> 6;

    auto STAGE = [&](const unsigned short* __restrict__ src, int ld, int base,
                     int ts, int half, int matoff, unsigned bo) {
        const int k0 = ts * 64;
        const int rowb = half * 128 + w * 16;
        #pragma unroll
        for (int kk = 0; kk < 2; ++kk) {
            const unsigned short* g = src + (size_t)(base + rowb + rloc) * ld
                                          + (k0 + kk * 32 + cloc * 8);
            __builtin_amdgcn_global_load_lds((const glb_u32*)g,
                (lds_u32*)&lds[bo + matoff + kk * 8192 + rowb * 32], 16, 0, 0);
        }
    };

    // prologue: tile0 fully + tile1 {A0,A1,B0}
    STAGE(Ab, lda, m0, 0, 0, 0, 0);      STAGE(Ab, lda, m0, 0, 1, 0, 0);
    STAGE(Bb, ldb, n0, 0, 0, 16384, 0);  STAGE(Bb, ldb, n0, 0, 1, 16384, 0);
    STAGE(Ab, lda, m0, 1, 0, 0, 32768);  STAGE(Ab, lda, m0, 1, 1, 0, 32768);
    STAGE(Bb, ldb, n0, 1, 0, 16384, 32768);
    asm volatile("s_waitcnt vmcnt(6)" ::: "memory");
    __builtin_amdgcn_s_barrier();

    for (int t = 0; t < NT; ++t) {
        const unsigned bo = (unsigned)(t & 1) * 32768u;
        const unsigned nbo = bo ^ 32768u;
        const int tp1 = (t + 1 < NT) ? t + 1 : NT - 1;
        const int tp2 = (t + 2 < NT) ? t + 2 : NT - 1;

        s16x8 af[8][2], bfv[4][2];
        // ---- phase 1: all 24 frag reads + stage B1(t+1) ----
        #pragma unroll
        for (int i = 0; i < 8; ++i)
            #pragma unroll
            for (int kk = 0; kk < 2; ++kk)
                af[i][kk] = *(const s16x8*)&lds[bo + kk * 8192 + (wr * 128 + i * 16) * 32 + rdlane];
        #pragma unroll
        for (int j = 0; j < 4; ++j)
            #pragma unroll
            for (int kk = 0; kk < 2; ++kk)
                bfv[j][kk] = *(const s16x8*)&lds[bo + 16384 + kk * 8192 + (wc * 64 + j * 16) * 32 + rdlane];
        STAGE(Bb, ldb, n0, tp1, 1, 16384, nbo);
        __builtin_amdgcn_s_barrier();
        asm volatile("s_waitcnt lgkmcnt(0)" ::: "memory");
        __builtin_amdgcn_s_setprio(1);
        #pragma unroll
        for (int i = 0; i < 4; ++i)
            #pragma unroll
            for (int j = 0; j < 2; ++j)
                #pragma unroll
                for (int kk = 0; kk < 2; ++kk)
                    acc[i][j] = __builtin_amdgcn_mfma_f32_16x16x32_bf16(af[i][kk], bfv[j][kk], acc[i][j], 0, 0, 0);
        __builtin_amdgcn_s_setprio(0);
        __builtin_amdgcn_s_barrier();
        // ---- phase 2: stage A0(t+2) into current buf ----
        STAGE(Ab, lda, m0, tp2, 0, 0, bo);
        __builtin_amdgcn_s_barrier();
        __builtin_amdgcn_s_setprio(1);
        #pragma unroll
        for (int i = 0; i < 4; ++i)
            #pragma unroll
            for (int j = 0; j < 2; ++j)
                #pragma unroll
                for (int kk = 0; kk < 2; ++kk)
                    acc[i][2 + j] = __builtin_amdgcn_mfma_f32_16x16x32_bf16(af[i][kk], bfv[2 + j][kk], acc[i][2 + j], 0, 0, 0);
        __builtin_amdgcn_s_setprio(0);
        __builtin_amdgcn_s_barrier();
        // ---- phase 3: stage A1(t+2) ----
        STAGE(Ab, lda, m0, tp2, 1, 0, bo);
        __builtin_amdgcn_s_barrier();
        __builtin_amdgcn_s_setprio(1);
        #pragma unroll
        for (int i = 0; i < 4; ++i)
            #pragma unroll
            for (int j = 0; j < 2; ++j)
                #pragma unroll
                for (int kk = 0; kk < 2; ++kk)
                    acc[4 + i][j] = __builtin_amdgcn_mfma_f32_16x16x32_bf16(af[4 + i][kk], bfv[j][kk], acc[4 + i][j], 0, 0, 0);
        __builtin_amdgcn_s_setprio(0);
        __builtin_amdgcn_s_barrier();
        // ---- phase 4: stage B0(t+2), counted vmcnt ----
        STAGE(Bb, ldb, n0, tp2, 0, 16384, bo);
        __builtin_amdgcn_s_barrier();
        __builtin_amdgcn_s_setprio(1);
        #pragma unroll
        for (int i = 0; i < 4; ++i)
            #pragma unroll
            for (int j = 0; j < 2; ++j)
                #pragma unroll
                for (int kk = 0; kk < 2; ++kk)
                    acc[4 + i][2 + j] = __builtin_amdgcn_mfma_f32_16x16x32_bf16(af[4 + i][kk], bfv[2 + j][kk], acc[4 + i][2 + j], 0, 0, 0);
        __builtin_amdgcn_s_setprio(0);
        asm volatile("s_waitcnt vmcnt(6)" ::: "memory");
        __builtin_amdgcn_s_barrier();
    }

    // ---------------- epilogue ----------------
    if constexpr (EPI == 1) {
        float* Cb = (float*)Cout + (size_t)bz * sCz;
        #pragma unroll
        for (int j = 0; j < 4; ++j) {
            const int ncol = n0 + wc * 64 + j * 16 + fr;
            #pragma unroll
            for (int i = 0; i < 8; ++i)
                #pragma unroll
                for (int r = 0; r < 4; ++r) {
                    const int mrow = m0 + wr * 128 + i * 16 + ch * 4 + r;
                    Cb[(size_t)mrow * ldc + ncol] = acc[i][j][r];
                }
        }
    } else {
        unsigned short* Cb = (unsigned short*)Cout + (size_t)bz * sCz;
        const unsigned char* mb = (EPI == 0) ? mask + (size_t)bz * maskStride : nullptr;
        #pragma unroll
        for (int j = 0; j < 4; ++j) {
            const int ncol = n0 + wc * 64 + j * 16 + fr;
            bool msk = false; float bn = 0.f;
            if constexpr (EPI == 0) msk = mb[ncol] != 0;
            if constexpr (EPI == 2) bn = bias[ncol];
            #pragma unroll
            for (int i = 0; i < 8; ++i) {
                #pragma unroll
                for (int r = 0; r < 4; ++r) {
                    const int mrow = m0 + wr * 128 + i * 16 + ch * 4 + r;
                    float val;
                    if constexpr (EPI == 0)      val = msk ? 1e-9f : acc[i][j][r] * scale;
                    else if constexpr (EPI == 2) val = acc[i][j][r] + bn;
                    else                         val = acc[i][j][r] + bias[mrow];
                    Cb[(size_t)mrow * ldc + ncol] = f2bf(val);
                }
            }
        }
    }
}

// ---------------------------------------------------------------------------
// Row softmax over S_=2048 bf16 scores, in place.
// ---------------------------------------------------------------------------
__global__ __launch_bounds__(256) void softmax_kernel(unsigned short* __restrict__ P)
{
    const int row = blockIdx.x;
    const int tid = threadIdx.x;
    unsigned short* prow = P + (size_t)row * S_;
    u16x8 v = *(const u16x8*)&prow[tid * 8];
    float f[8];
    #pragma unroll
    for (int j = 0; j < 8; ++j) f[j] = bf2f(v[j]);
    float m = f[0];
    #pragma unroll
    for (int j = 1; j < 8; ++j) m = fmaxf(m, f[j]);
    #pragma unroll
    for (int o = 1; o < 64; o <<= 1) m = fmaxf(m, __shfl_xor(m, o, 64));
    __shared__ float smax[4], ssum[4];
    const int w = tid >> 6, lane = tid & 63;
    if (lane == 0) smax[w] = m;
    __syncthreads();
    m = fmaxf(fmaxf(smax[0], smax[1]), fmaxf(smax[2], smax[3]));
    float e[8], s = 0.f;
    #pragma unroll
    for (int j = 0; j < 8; ++j) { e[j] = expf(f[j] - m); s += e[j]; }
    #pragma unroll
    for (int o = 1; o < 64; o <<= 1) s += __shfl_xor(s, o, 64);
    if (lane == 0) ssum[w] = s;
    __syncthreads();
    s = ssum[0] + ssum[1] + ssum[2] + ssum[3];
    const float inv = 1.0f / s;
    u16x8 o8;
    #pragma unroll
    for (int j = 0; j < 8; ++j) o8[j] = f2bf(e[j] * inv);
    *(u16x8*)&prow[tid * 8] = o8;
}

// ---------------------------------------------------------------------------
extern "C" void kernel_launch(void* const* d_in, const int* in_sizes, int n_in,
                              void* d_out, int out_size, void* d_ws, size_t ws_size,
                              hipStream_t stream)
{
    const float* x  = (const float*)d_in[0];
    const float* Wq = (const float*)d_in[1];
    const float* bq = (const float*)d_in[2];
    const float* Wk = (const float*)d_in[3];
    const float* bk = (const float*)d_in[4];
    const float* Wv = (const float*)d_in[5];
    const float* bv = (const float*)d_in[6];
    const unsigned char* mraw = (const unsigned char*)d_in[7];

    const int BS = B_ * S_;                      // 16384
    unsigned short* Qb = (unsigned short*)d_ws;
    unsigned short* Kb = Qb + (size_t)BS * E_;
    unsigned short* VT = Kb + (size_t)BS * E_;
    unsigned short* Sc = VT + (size_t)BS * E_;
    unsigned short* xb = Sc;                                    // aliases Sc
    unsigned short* Wqb = Sc + (size_t)BS * E_;
    unsigned short* Wkb = Wqb + (size_t)E_ * E_;
    unsigned short* Wvb = Wkb + (size_t)E_ * E_;
    unsigned char* mcanon = (unsigned char*)(Sc + (size_t)B_ * S_ * S_);

    mask_canon_kernel<<<1, 256, 0, stream>>>(mraw, mcanon, BS);

    cvt_bf16_kernel<<<2048, 256, 0, stream>>>(x, xb, BS * E_ / 8);
    cvt_bf16_kernel<<<512, 256, 0, stream>>>(Wq, Wqb, E_ * E_ / 8);
    cvt_bf16_kernel<<<512, 256, 0, stream>>>(Wk, Wkb, E_ * E_ / 8);
    cvt_bf16_kernel<<<512, 256, 0, stream>>>(Wv, Wvb, E_ * E_ / 8);

    // Q = xb @ Wq^T + bq ; K = xb @ Wk^T + bk   (bf16 [BS][E])
    gemm256<2><<<dim3(E_ / 256, BS / 256), 512, 0, stream>>>(
        xb, Wqb, (void*)Qb, 0, 0, 0, E_, E_, E_, E_, nullptr, 0, 1.0f, bq);
    gemm256<2><<<dim3(E_ / 256, BS / 256), 512, 0, stream>>>(
        xb, Wkb, (void*)Kb, 0, 0, 0, E_, E_, E_, E_, nullptr, 0, 1.0f, bk);
    // VT[e][bs] = Wv[e,:] . x[bs,:] + bv[e]
    gemm256<3><<<dim3(BS / 256, E_ / 256), 512, 0, stream>>>(
        Wvb, xb, (void*)VT, 0, 0, 0, E_, E_, BS, E_, nullptr, 0, 1.0f, bv);

    // scores = (Q.K^T)/32, mask fill 1e-9, bf16
    gemm256<0><<<dim3(S_ / 256, S_ / 256, B_), 512, 0, stream>>>(
        Qb, Kb, (void*)Sc,
        (long long)S_ * E_, (long long)S_ * E_, (long long)S_ * S_,
        E_, E_, S_, E_, mcanon, S_, 0.03125f, nullptr);

    softmax_kernel<<<dim3(BS), 256, 0, stream>>>(Sc);

    // out = P . V (via V^T, NT)
    gemm256<1><<<dim3(E_ / 256, S_ / 256, B_), 512, 0, stream>>>(
        Sc, VT, d_out,
        (long long)S_ * S_, (long long)S_, (long long)S_ * E_,
        S_, BS, E_, S_, nullptr, 0, 1.0f, nullptr);
}